// Round 5
// baseline (89.013 us; speedup 1.0000x reference)
//
#include <hip/hip_runtime.h>

// Difference3DCostVolume: out[b,c,d,h,w] = l[b,c,h,w] - r[b,c,h,w-d], pad 1.0 for w<d
// Shapes: l,r [B=2, C=32, H=128, W=240] f32; out [B, C, D=48, H, W] f32.
// Write-BW bound: 377.5 MB out. Fill-kernel ceiling on this chip: ~6.9 TB/s -> ~57-62 us.
//
// R4: R2 structure exactly (best so far, 77.5 us), single change: PLAIN stores
// instead of nontemporal (ablating the nt flag — fill kernel uses plain stores
// and hits 6.9 TB/s).

#define MAX_DISP 48
#define HH 128
#define WW 240
#define NV 60            // float4 per row
#define PAD4 12          // 12 float4 = 48 floats of front padding

typedef float f32x4 __attribute__((ext_vector_type(4)));

__global__ __launch_bounds__(256) void costvol_kernel(
    const f32x4* __restrict__ l4,
    const float* __restrict__ r,
    f32x4* __restrict__ out4)
{
    __shared__ float r_pad[48 + WW];   // 288 floats = 72 float4

    const int bch = blockIdx.x;        // bc*H + h
    const int h   = bch % HH;
    const int bc  = bch / HH;
    const int tid = threadIdx.x;
    const int v   = tid & 63;          // float4 index along W (0..59 active)
    const int kg  = tid >> 6;          // 0..3 -> d-group base

    // Stage r row into padded LDS; pad front with 0 (masked by w>=d anyway).
    if (tid < 48)  r_pad[tid] = 0.0f;
    if (tid < WW)  r_pad[48 + tid] = r[(size_t)bch * WW + tid];

    // l as float4, register-resident
    f32x4 lv = {0.f, 0.f, 0.f, 0.f};
    if (v < NV) lv = ((const f32x4*)l4)[(size_t)bch * NV + v];
    __syncthreads();

    if (v >= NV) return;

    const f32x4* rp4 = (const f32x4*)r_pad;
    const size_t  dstride4 = (size_t)HH * NV;            // float4 stride per d
    const int     w0 = 4 * v;                            // first w this thread owns

    #pragma unroll
    for (int iter = 0; iter < 3; ++iter) {
        const int k  = kg + 4 * iter;                    // wave-uniform
        const int d0 = 4 * k;

        // aligned, lane-consecutive LDS reads (conflict-free ds_read_b128)
        f32x4 A = rp4[PAD4 + v - k];                     // r[w0-d0 .. w0-d0+3]
        f32x4 B = rp4[PAD4 + v - k - 1];                 // r[w0-d0-4 .. w0-d0-1]

        size_t ob = ((size_t)(bc * MAX_DISP + d0) * HH + h) * NV + v;

        #pragma unroll
        for (int s = 0; s < 4; ++s) {                    // d = d0 + s
            f32x4 o;
            #pragma unroll
            for (int j = 0; j < 4; ++j) {                // w = w0 + j
                const int src = j - s;                   // compile-time
                float rv = (src >= 0) ? A[src] : B[4 + src];
                o[j] = (w0 + j >= d0 + s) ? (lv[j] - rv) : 1.0f;
            }
            out4[ob + (size_t)s * dstride4] = o;         // plain store (no nt)
        }
    }
}

extern "C" void kernel_launch(void* const* d_in, const int* in_sizes, int n_in,
                              void* d_out, int out_size, void* d_ws, size_t ws_size,
                              hipStream_t stream) {
    const f32x4* l4 = (const f32x4*)d_in[0];
    const float* r  = (const float*)d_in[1];
    f32x4* out4 = (f32x4*)d_out;

    const int nblocks = 2 * 32 * HH;   // B*C*H = 8192
    costvol_kernel<<<nblocks, 256, 0, stream>>>(l4, r, out4);
}

// Round 6
// 80.006 us; speedup vs baseline: 1.1126x; 1.1126x over previous
//
#include <hip/hip_runtime.h>

// Difference3DCostVolume: out[b,c,d,h,w] = l[b,c,h,w] - r[b,c,h,w-d], pad 1.0 for w<d
// Shapes: l,r [B=2, C=32, H=128, W=240] f32; out [B, C, D=48, H, W] f32.
// Write-BW bound: 377.5 MB out. Fill ceiling on this chip: ~6.9 TB/s -> ~57-62 us.
//
// R5: d-major blocks. One block per (bc, d) writes ONE contiguous 122.8 KB
// slab (fill-kernel pattern) with nt stores. r-shift is block-uniform: two
// aligned f32x4 loads + funnel select templated on (-d)&3. No LDS; l/r reads
// are L2-cached (48x reuse per bc).

#define MAX_DISP 48
#define HH 128
#define NV 60                      // f32x4 per row
#define SLAB (HH * NV)             // 7680 f32x4 per (bc,d) slab

typedef float f32x4 __attribute__((ext_vector_type(4)));

template <int M>
__device__ __forceinline__ void slab_loop(
    const f32x4* __restrict__ l4, const f32x4* __restrict__ r4,
    f32x4* __restrict__ out4, size_t inbase, size_t obase, int d)
{
    for (int i = threadIdx.x; i < SLAB; i += 256) {
        const int h  = i / NV;
        const int v  = i - h * NV;
        const int w0 = 4 * v;
        const f32x4 lv = l4[inbase + i];

        const int idx = w0 - d;          // may be negative
        const int q   = idx >> 2;        // arithmetic shift = floor
        const size_t rrow = inbase + (size_t)h * NV;
        f32x4 A = (q >= 0) ? r4[rrow + q] : (f32x4){0.f, 0.f, 0.f, 0.f};
        const int qb = (q + 1 < NV - 1) ? q + 1 : NV - 1;     // clamp (B unused when M==0 && q==59)
        f32x4 B = (q + 1 >= 0) ? r4[rrow + qb] : (f32x4){0.f, 0.f, 0.f, 0.f};

        f32x4 win;
        #pragma unroll
        for (int t = 0; t < 4; ++t)
            win[t] = (M + t < 4) ? A[M + t] : B[M + t - 4];

        f32x4 o;
        #pragma unroll
        for (int j = 0; j < 4; ++j)
            o[j] = (w0 + j >= d) ? (lv[j] - win[j]) : 1.0f;

        __builtin_nontemporal_store(o, &out4[obase + i]);
    }
}

__global__ __launch_bounds__(256) void costvol_kernel(
    const f32x4* __restrict__ l4,
    const f32x4* __restrict__ r4,
    f32x4* __restrict__ out4)
{
    const int blk = blockIdx.x;          // bc*48 + d
    const int d   = blk % MAX_DISP;
    const int bc  = blk / MAX_DISP;

    const size_t inbase = (size_t)bc * SLAB;     // f32x4 index of (bc) plane
    const size_t obase  = (size_t)blk * SLAB;    // contiguous output slab

    switch ((-d) & 3) {
        case 0: slab_loop<0>(l4, r4, out4, inbase, obase, d); break;
        case 1: slab_loop<1>(l4, r4, out4, inbase, obase, d); break;
        case 2: slab_loop<2>(l4, r4, out4, inbase, obase, d); break;
        case 3: slab_loop<3>(l4, r4, out4, inbase, obase, d); break;
    }
}

extern "C" void kernel_launch(void* const* d_in, const int* in_sizes, int n_in,
                              void* d_out, int out_size, void* d_ws, size_t ws_size,
                              hipStream_t stream) {
    const f32x4* l4 = (const f32x4*)d_in[0];
    const f32x4* r4 = (const f32x4*)d_in[1];
    f32x4* out4 = (f32x4*)d_out;

    const int nblocks = 64 * MAX_DISP;   // 3072 blocks, one 122.8 KB slab each
    costvol_kernel<<<nblocks, 256, 0, stream>>>(l4, r4, out4);
}

// Round 7
// 78.623 us; speedup vs baseline: 1.1322x; 1.0176x over previous
//
#include <hip/hip_runtime.h>

// Difference3DCostVolume: out[b,c,d,h,w] = l[b,c,h,w] - r[b,c,h,w-d], pad 1.0 for w<d
// Shapes: l,r [B=2, C=32, H=128, W=240] f32; out [B, C, D=48, H, W] f32.
// Write-BW bound: 377.5 MB out. Fill ceiling on this chip: ~6.9 TB/s (plain, full-line).
//
// R6: R3 structure (960-thread blocks, 16 h-rows, all wave-stores 1024B-aligned
// full cache lines, inputs read exactly once) + PLAIN stores (flip nt->plain).
// Tests the {plain x full-line} cell: nt path appears capped ~5 TB/s; plain
// partial-line triggers RFO (R4, 89us). Plain + full-line should avoid both.

#define MAX_DISP 48
#define HH 128
#define WW 240
#define NV 60              // float4 per row
#define PAD4 12            // 12 float4 = 48 floats front pad per row
#define ROW4 (PAD4 + NV)   // 72 float4 per LDS row
#define HG 16              // rows per block

typedef float f32x4 __attribute__((ext_vector_type(4)));

__global__ __launch_bounds__(960) void costvol_kernel(
    const f32x4* __restrict__ l4,
    const f32x4* __restrict__ r4,
    f32x4* __restrict__ out4)
{
    __shared__ f32x4 r_lds[HG * ROW4];   // 16 rows x 72 f32x4 = 18.4 KB

    const int bc  = blockIdx.x & 63;     // 0..63
    const int hg  = blockIdx.x >> 6;     // 0..7
    const int h0  = hg * HG;
    const int tid = threadIdx.x;         // 0..959
    const int hl  = tid / NV;            // 0..15 row within group
    const int v   = tid % NV;            // 0..59 float4 within row

    // zero the 12-f32x4 front pad of each row (192 slots)
    if (tid < HG * PAD4) {
        r_lds[(tid / PAD4) * ROW4 + (tid % PAD4)] = (f32x4){0.f, 0.f, 0.f, 0.f};
    }
    // stage 16 rows of r: one f32x4 per thread, coalesced; read exactly once
    const size_t in_base = ((size_t)bc * HH + h0) * NV;   // f32x4 index
    r_lds[hl * ROW4 + PAD4 + v] = r4[in_base + tid];
    // l slab, register-resident; read exactly once
    const f32x4 lv = l4[in_base + tid];
    __syncthreads();

    const int w0 = 4 * v;
    // out f32x4 index for d=0: ((bc*48 + 0)*128 + h0 + hl)*60 + v
    size_t ob = ((size_t)bc * MAX_DISP * HH + h0 + hl) * NV + v;
    const size_t dstride4 = (size_t)HH * NV;   // 7680 f32x4 per d

    #pragma unroll
    for (int k = 0; k < MAX_DISP / 4; ++k) {   // d-group d = 4k..4k+3
        const int d0 = 4 * k;
        const f32x4 A = r_lds[hl * ROW4 + PAD4 + v - k];       // r[w0-d0 ..]
        const f32x4 B = r_lds[hl * ROW4 + PAD4 + v - k - 1];   // r[w0-d0-4 ..]

        #pragma unroll
        for (int s = 0; s < 4; ++s) {          // d = d0 + s
            f32x4 o;
            #pragma unroll
            for (int j = 0; j < 4; ++j) {      // w = w0 + j
                const int src = j - s;         // compile-time
                float rv = (src >= 0) ? A[src] : B[4 + src];
                o[j] = (w0 + j >= d0 + s) ? (lv[j] - rv) : 1.0f;
            }
            out4[ob + (size_t)(d0 + s) * dstride4] = o;   // PLAIN store (full-line traffic)
        }
    }
}

extern "C" void kernel_launch(void* const* d_in, const int* in_sizes, int n_in,
                              void* d_out, int out_size, void* d_ws, size_t ws_size,
                              hipStream_t stream) {
    const f32x4* l4 = (const f32x4*)d_in[0];
    const f32x4* r4 = (const f32x4*)d_in[1];
    f32x4* out4 = (f32x4*)d_out;

    const int nblocks = 64 * (HH / HG);   // 512
    costvol_kernel<<<nblocks, 960, 0, stream>>>(l4, r4, out4);
}